// Round 2
// baseline (467.549 us; speedup 1.0000x reference)
//
#include <hip/hip_runtime.h>
#include <hip/hip_bf16.h>
#include <hip/hip_fp16.h>

#define NN   10000
#define FIN  512
#define FOUT 256
#define NPAD 10240
#define LRA  0.2f
#define JT   256

typedef __attribute__((ext_vector_type(4))) float    f32x4;
typedef __attribute__((ext_vector_type(4))) int      i32x4;
typedef __attribute__((ext_vector_type(8))) _Float16 f16x8;
typedef __attribute__((ext_vector_type(8))) short    bf16x8;

static __device__ __forceinline__ short f2bf(float x) {
  unsigned u = __builtin_bit_cast(unsigned, x);
  u += 0x7fffu + ((u >> 16) & 1u);   // RNE; x always finite here
  return (short)(u >> 16);
}

// K0: Wt[c][k] = f16(W[k][c])   (512x256 -> 256x512)
__global__ __launch_bounds__(256) void k0_wt(const float* __restrict__ W,
                                             _Float16* __restrict__ Wt) {
  int idx = blockIdx.x * 256 + threadIdx.x;
  int k = idx >> 8, c = idx & 255;
  Wt[(size_t)c * FIN + k] = (_Float16)W[(size_t)k * FOUT + c];
}

// K1: Wh = h @ W via f16 MFMA, fp32 accum. BM=64, BN=256, 4 waves n-split.
__global__ __launch_bounds__(256) void k1_wh(const float* __restrict__ h,
                                             const _Float16* __restrict__ Wt,
                                             float* __restrict__ Wh) {
  const int r0 = blockIdx.x * 64;
  const int t = threadIdx.x;
  const int w = t >> 6, l = t & 63;
  const int lr = l & 15, lq = l >> 4;
  f32x4 acc[4][4];
#pragma unroll
  for (int m = 0; m < 4; ++m)
#pragma unroll
    for (int n = 0; n < 4; ++n)
#pragma unroll
      for (int q = 0; q < 4; ++q) acc[m][n][q] = 0.f;

  for (int kk = 0; kk < FIN; kk += 32) {
    f16x8 af[4];
#pragma unroll
    for (int m = 0; m < 4; ++m) {
      int gr = r0 + m * 16 + lr;
      if (gr < NN) {
        const f32x4* p = (const f32x4*)(h + (size_t)gr * FIN + kk + lq * 8);
        f32x4 v0 = p[0], v1 = p[1];
#pragma unroll
        for (int i = 0; i < 4; ++i) { af[m][i] = (_Float16)v0[i]; af[m][i + 4] = (_Float16)v1[i]; }
      } else {
#pragma unroll
        for (int i = 0; i < 8; ++i) af[m][i] = (_Float16)0.f;
      }
    }
#pragma unroll
    for (int n = 0; n < 4; ++n) {
      int gc = w * 64 + n * 16 + lr;
      f16x8 bf = *(const f16x8*)(Wt + (size_t)gc * FIN + kk + lq * 8);
#pragma unroll
      for (int m = 0; m < 4; ++m)
        acc[m][n] = __builtin_amdgcn_mfma_f32_16x16x32_f16(af[m], bf, acc[m][n], 0, 0, 0);
    }
  }
#pragma unroll
  for (int m = 0; m < 4; ++m)
#pragma unroll
    for (int n = 0; n < 4; ++n)
#pragma unroll
      for (int q = 0; q < 4; ++q) {
        int gr = r0 + m * 16 + lq * 4 + q;
        if (gr < NN) Wh[(size_t)gr * FOUT + w * 64 + n * 16 + lr] = acc[m][n][q];
      }
}

// K2: e1/e2 (padded to NPAD) and WhT[c][r] = bf16(Wh[r][c]), r-dim padded to NPAD.
__global__ __launch_bounds__(256) void k2_et(const float* __restrict__ Wh,
                                             const float* __restrict__ a,
                                             float* __restrict__ e1,
                                             float* __restrict__ e2,
                                             short* __restrict__ WhT) {
  __shared__ float tile[64][65];
  const int r0 = blockIdx.x * 64;
  const int t = threadIdx.x;
  {
    int r = r0 + (t >> 2);
    int sub = t & 3;
    float s1 = 0.f, s2 = 0.f;
    if (r < NN) {
      for (int i = 0; i < 64; ++i) {
        int c = sub + 4 * i;
        float v = Wh[(size_t)r * FOUT + c];
        s1 += v * a[c];
        s2 += v * a[FOUT + c];
      }
    }
    s1 += __shfl_xor(s1, 1); s1 += __shfl_xor(s1, 2);
    s2 += __shfl_xor(s2, 1); s2 += __shfl_xor(s2, 2);
    if (sub == 0) {
      e1[r] = (r < NN) ? s1 : 0.f;
      e2[r] = (r < NN) ? s2 : 0.f;
    }
  }
  for (int c0 = 0; c0 < FOUT; c0 += 64) {
    __syncthreads();
#pragma unroll
    for (int i = 0; i < 16; ++i) {
      int e = t + 256 * i;
      int row = e >> 6, col = e & 63;
      int grd = r0 + row;
      tile[row][col] = (grd < NN) ? Wh[(size_t)grd * FOUT + c0 + col] : 0.f;
    }
    __syncthreads();
#pragma unroll
    for (int i = 0; i < 16; ++i) {
      int e = t + 256 * i;
      int c = e >> 6, rr = e & 63;
      WhT[(size_t)(c0 + c) * NPAD + r0 + rr] = f2bf(tile[rr][c]);
    }
  }
}

// K3: fused masked-softmax @ Wh. BM=32, 512 threads (8 waves n-split 32 cols),
// JT=256 j-tiles, double-buffered P LDS (1 barrier/tile), 2-tile ping-pong
// register prefetch of adj (deep enough to cover ~900cy HBM latency).
// Thread t owns row t>>4, cols {psub*8..+7} U {128+psub*8..+7} of the tile.
#define LOAD_TILE(J0N, AV, EV)                                              \
  {                                                                         \
    const int jn_ = (J0N) + jb;                                             \
    EV[0] = *(const f32x4*)(e2 + jn_);                                      \
    EV[1] = *(const f32x4*)(e2 + jn_ + 4);                                  \
    EV[2] = *(const f32x4*)(e2 + jn_ + 128);                                \
    EV[3] = *(const f32x4*)(e2 + jn_ + 132);                                \
    if (rowok && (J0N) + JT <= NN) {                                        \
      AV[0] = *(const i32x4*)(adj + adjrow + jn_);                          \
      AV[1] = *(const i32x4*)(adj + adjrow + jn_ + 4);                      \
      AV[2] = *(const i32x4*)(adj + adjrow + jn_ + 128);                    \
      AV[3] = *(const i32x4*)(adj + adjrow + jn_ + 132);                    \
    } else {                                                                \
      _Pragma("unroll")                                                     \
      for (int p_ = 0; p_ < 4; ++p_) {                                      \
        _Pragma("unroll")                                                   \
        for (int i_ = 0; i_ < 4; ++i_) {                                    \
          int j_ = jn_ + (p_ >> 1) * 128 + (p_ & 1) * 4 + i_;               \
          AV[p_][i_] = (rowok && j_ < NN) ? adj[adjrow + j_] : 0;           \
        }                                                                   \
      }                                                                     \
    }                                                                       \
  }

#define PHASE(J0, AV, EV, BUF)                                              \
  {                                                                         \
    bf16x8 pf0, pf1;                                                        \
    _Pragma("unroll")                                                       \
    for (int i = 0; i < 8; ++i) {                                           \
      float x = e1v + EV[i >> 2][i & 3];                                    \
      float s = fmaxf(x, LRA * x);                                          \
      float p = (AV[i >> 2][i & 3] > 0) ? __expf(s) : 0.f;                  \
      rs += p; pf0[i] = f2bf(p);                                            \
    }                                                                       \
    _Pragma("unroll")                                                       \
    for (int i = 0; i < 8; ++i) {                                           \
      float x = e1v + EV[2 + (i >> 2)][i & 3];                              \
      float s = fmaxf(x, LRA * x);                                          \
      float p = (AV[2 + (i >> 2)][i & 3] > 0) ? __expf(s) : 0.f;            \
      rs += p; pf1[i] = f2bf(p);                                            \
    }                                                                       \
    {                                                                       \
      char* wb_ = (BUF) + prow * 512;                                       \
      const int sw_ = (prow & 7) << 4;                                      \
      *(bf16x8*)(wb_ + ((psub * 16) ^ sw_)) = pf0;                          \
      *(bf16x8*)(wb_ + ((256 + psub * 16) ^ sw_)) = pf1;                    \
    }                                                                       \
    __syncthreads();                                                        \
    _Pragma("unroll")                                                       \
    for (int kt = 0; kt < 8; ++kt) {                                        \
      const int boff_ = (kt * 64 + lq * 16) ^ ((lr & 7) << 4);              \
      bf16x8 a0 = *(const bf16x8*)((BUF) + lr * 512 + boff_);               \
      bf16x8 a1 = *(const bf16x8*)((BUF) + (16 + lr) * 512 + boff_);        \
      const short* bp_ = WhT + (J0) + kt * 32 + lq * 8;                     \
      bf16x8 b0 = *(const bf16x8*)(bp_ + bcol0);                            \
      bf16x8 b1 = *(const bf16x8*)(bp_ + bcol1);                            \
      acc[0][0] = __builtin_amdgcn_mfma_f32_16x16x32_bf16(a0, b0, acc[0][0], 0, 0, 0); \
      acc[1][0] = __builtin_amdgcn_mfma_f32_16x16x32_bf16(a1, b0, acc[1][0], 0, 0, 0); \
      acc[0][1] = __builtin_amdgcn_mfma_f32_16x16x32_bf16(a0, b1, acc[0][1], 0, 0, 0); \
      acc[1][1] = __builtin_amdgcn_mfma_f32_16x16x32_bf16(a1, b1, acc[1][1], 0, 0, 0); \
    }                                                                       \
  }

__global__ __launch_bounds__(512) void k3_main(const int* __restrict__ adj,
                                               const float* __restrict__ e1,
                                               const float* __restrict__ e2,
                                               const short* __restrict__ WhT,
                                               float* __restrict__ out) {
  __shared__ __align__(16) char Plds[2][32 * 512];   // 2 x (32 rows x 256 bf16)
  __shared__ float rowsum[32];
  const int r0 = blockIdx.x * 32;
  const int t = threadIdx.x;
  const int w = t >> 6, l = t & 63;
  const int lr = l & 15, lq = l >> 4;
  const int prow = t >> 4;        // 0..31
  const int psub = t & 15;
  const int jb = psub * 8;
  const int gr = r0 + prow;
  const bool rowok = (gr < NN);
  const float e1v = rowok ? e1[gr] : 0.f;
  const size_t adjrow = (size_t)gr * NN;
  const size_t bcol0 = (size_t)(w * 32 + lr) * NPAD;
  const size_t bcol1 = (size_t)(w * 32 + 16 + lr) * NPAD;
  float rs = 0.f;
  f32x4 acc[2][2];
#pragma unroll
  for (int m = 0; m < 2; ++m)
#pragma unroll
    for (int n = 0; n < 2; ++n)
#pragma unroll
      for (int q = 0; q < 4; ++q) acc[m][n][q] = 0.f;

  const int NT = (NN + JT - 1) / JT;   // 40 (even)
  i32x4 avA[4], avB[4];
  f32x4 evA[4], evB[4];
  LOAD_TILE(0, avA, evA);

  for (int jt = 0; jt < NT; jt += 2) {
    LOAD_TILE((jt + 1) * JT, avB, evB);          // prefetch tile jt+1
    PHASE(jt * JT, avA, evA, &Plds[0][0]);
    if (jt + 2 < NT) LOAD_TILE((jt + 2) * JT, avA, evA);  // prefetch tile jt+2
    PHASE((jt + 1) * JT, avB, evB, &Plds[1][0]);
  }

  rs += __shfl_xor(rs, 1); rs += __shfl_xor(rs, 2);
  rs += __shfl_xor(rs, 4); rs += __shfl_xor(rs, 8);
  if (psub == 0) rowsum[prow] = rs;
  __syncthreads();
#pragma unroll
  for (int m = 0; m < 2; ++m)
#pragma unroll
    for (int n = 0; n < 2; ++n)
#pragma unroll
      for (int q = 0; q < 4; ++q) {
        int row = m * 16 + lq * 4 + q;
        int grow = r0 + row;
        if (grow < NN) {
          float v = acc[m][n][q] / rowsum[row];
          float o = (v > 0.f) ? v : (__expf(v) - 1.f);
          out[(size_t)grow * FOUT + w * 32 + n * 16 + lr] = o;
        }
      }
}

extern "C" void kernel_launch(void* const* d_in, const int* in_sizes, int n_in,
                              void* d_out, int out_size, void* d_ws, size_t ws_size,
                              hipStream_t stream) {
  const float* h   = (const float*)d_in[0];
  const int*   adj = (const int*)d_in[1];
  const float* W   = (const float*)d_in[2];
  const float* a   = (const float*)d_in[3];
  float* out = (float*)d_out;
  char* ws = (char*)d_ws;
  // ws layout:
  _Float16* Wt  = (_Float16*)(ws + 0);          // 262144
  float*    Wh  = (float*)(ws + 262144);        // 10240000 -> 10502144
  short*    WhT = (short*)(ws + 10502144);      // 256*10240*2 = 5242880 -> 15745024
  float*    e1  = (float*)(ws + 15745024);      // 40960 -> 15785984
  float*    e2  = (float*)(ws + 15785984);      // 40960 -> 15826944
  (void)in_sizes; (void)n_in; (void)out_size; (void)ws_size;

  k0_wt<<<dim3(512), dim3(256), 0, stream>>>(W, Wt);
  k1_wh<<<dim3(157), dim3(256), 0, stream>>>(h, Wt, Wh);
  k2_et<<<dim3(160), dim3(256), 0, stream>>>(Wh, a, e1, e2, WhT);
  k3_main<<<dim3(313), dim3(512), 0, stream>>>(adj, e1, e2, WhT, out);
}

// Round 3
// 371.494 us; speedup vs baseline: 1.2586x; 1.2586x over previous
//
#include <hip/hip_runtime.h>
#include <hip/hip_bf16.h>
#include <hip/hip_fp16.h>

#define NN   10000
#define FIN  512
#define FOUT 256
#define NPAD 10240
#define LRA  0.2f

typedef __attribute__((ext_vector_type(4))) float    f32x4;
typedef __attribute__((ext_vector_type(4))) int      i32x4;
typedef __attribute__((ext_vector_type(8))) _Float16 f16x8;
typedef __attribute__((ext_vector_type(8))) short    bf16x8;

static __device__ __forceinline__ short f2bf(float x) {
  unsigned u = __builtin_bit_cast(unsigned, x);
  u += 0x7fffu + ((u >> 16) & 1u);   // RNE; x always finite here
  return (short)(u >> 16);
}
static __device__ __forceinline__ float bf2f(short s) {
  unsigned u = ((unsigned)(unsigned short)s) << 16;
  return __builtin_bit_cast(float, u);
}

// ---------------- K0: Wt[c][k] = f16(W[k][c]) ----------------
__global__ __launch_bounds__(256) void k0_wt(const float* __restrict__ W,
                                             _Float16* __restrict__ Wt) {
  int idx = blockIdx.x * 256 + threadIdx.x;
  int k = idx >> 8, c = idx & 255;
  Wt[(size_t)c * FIN + k] = (_Float16)W[(size_t)k * FOUT + c];
}

// ---------------- K1: Wh = h @ W (f16 MFMA, fp32 accum) ----------------
__global__ __launch_bounds__(256) void k1_wh(const float* __restrict__ h,
                                             const _Float16* __restrict__ Wt,
                                             float* __restrict__ Wh) {
  const int r0 = blockIdx.x * 64;
  const int t = threadIdx.x;
  const int w = t >> 6, l = t & 63;
  const int lr = l & 15, lq = l >> 4;
  f32x4 acc[4][4];
#pragma unroll
  for (int m = 0; m < 4; ++m)
#pragma unroll
    for (int n = 0; n < 4; ++n)
#pragma unroll
      for (int q = 0; q < 4; ++q) acc[m][n][q] = 0.f;

  for (int kk = 0; kk < FIN; kk += 32) {
    f16x8 af[4];
#pragma unroll
    for (int m = 0; m < 4; ++m) {
      int gr = r0 + m * 16 + lr;
      if (gr < NN) {
        const f32x4* p = (const f32x4*)(h + (size_t)gr * FIN + kk + lq * 8);
        f32x4 v0 = p[0], v1 = p[1];
#pragma unroll
        for (int i = 0; i < 4; ++i) { af[m][i] = (_Float16)v0[i]; af[m][i + 4] = (_Float16)v1[i]; }
      } else {
#pragma unroll
        for (int i = 0; i < 8; ++i) af[m][i] = (_Float16)0.f;
      }
    }
#pragma unroll
    for (int n = 0; n < 4; ++n) {
      int gc = w * 64 + n * 16 + lr;
      f16x8 bf = *(const f16x8*)(Wt + (size_t)gc * FIN + kk + lq * 8);
#pragma unroll
      for (int m = 0; m < 4; ++m)
        acc[m][n] = __builtin_amdgcn_mfma_f32_16x16x32_f16(af[m], bf, acc[m][n], 0, 0, 0);
    }
  }
#pragma unroll
  for (int m = 0; m < 4; ++m)
#pragma unroll
    for (int n = 0; n < 4; ++n)
#pragma unroll
      for (int q = 0; q < 4; ++q) {
        int gr = r0 + m * 16 + lq * 4 + q;
        if (gr < NN) Wh[(size_t)gr * FOUT + w * 64 + n * 16 + lr] = acc[m][n][q];
      }
}

// ---------------- K2: e1/e2 (padded) + WhT[c][r] bf16 ----------------
__global__ __launch_bounds__(256) void k2_et(const float* __restrict__ Wh,
                                             const float* __restrict__ a,
                                             float* __restrict__ e1,
                                             float* __restrict__ e2,
                                             short* __restrict__ WhT) {
  __shared__ float tile[64][65];
  const int r0 = blockIdx.x * 64;
  const int t = threadIdx.x;
  {
    int r = r0 + (t >> 2);
    int sub = t & 3;
    float s1 = 0.f, s2 = 0.f;
    if (r < NN) {
      for (int i = 0; i < 64; ++i) {
        int c = sub + 4 * i;
        float v = Wh[(size_t)r * FOUT + c];
        s1 += v * a[c];
        s2 += v * a[FOUT + c];
      }
    }
    s1 += __shfl_xor(s1, 1); s1 += __shfl_xor(s1, 2);
    s2 += __shfl_xor(s2, 1); s2 += __shfl_xor(s2, 2);
    if (sub == 0) {
      e1[r] = (r < NN) ? s1 : 0.f;
      e2[r] = (r < NN) ? s2 : 0.f;
    }
  }
  for (int c0 = 0; c0 < FOUT; c0 += 64) {
    __syncthreads();
#pragma unroll
    for (int i = 0; i < 16; ++i) {
      int e = t + 256 * i;
      int row = e >> 6, col = e & 63;
      int grd = r0 + row;
      tile[row][col] = (grd < NN) ? Wh[(size_t)grd * FOUT + c0 + col] : 0.f;
    }
    __syncthreads();
#pragma unroll
    for (int i = 0; i < 16; ++i) {
      int e = t + 256 * i;
      int c = e >> 6, rr = e & 63;
      WhT[(size_t)(c0 + c) * NPAD + r0 + rr] = f2bf(tile[rr][c]);
    }
  }
}

// ---------------- KP: bit-pack adj (400 MB -> 12.8 MB) ----------------
// word it = (row, w): bits j = w*64 + lane, lane i -> bit i.
__global__ __launch_bounds__(256) void kp_bits(const int* __restrict__ adj,
                                               unsigned long long* __restrict__ bits) {
  const int lane = threadIdx.x & 63;
  const int wid = (blockIdx.x * 256 + threadIdx.x) >> 6;
  const int nw = (gridDim.x * 256) >> 6;
  const int TOT = NPAD * (NPAD / 64);   // 1,638,400
  for (int it = wid; it < TOT; it += nw) {
    int row = it / (NPAD / 64);
    int w = it - row * (NPAD / 64);
    int j = w * 64 + lane;
    int v = 0;
    if (row < NN && j < NN) v = adj[(size_t)row * NN + j];
    unsigned long long m = __ballot(v > 0);
    if (lane == 0) bits[it] = m;
  }
}

// ---------------- K3: partial masked-softmax @ Wh ----------------
// Block = (rowblk: 256 rows) x (slice s of NPAD/nslice j-values).
// 512 thr = 8 waves n-split (32 cols each). P producers: thread t owns
// row t>>1, 32 j (sub=t&1). P double-buffered in XOR-swizzled LDS.
#define K3_PHASE(PH, BREG, BUF)                                               \
  {                                                                           \
    const int jg_ = jbase + (PH) * 64;                                        \
    bf16x8 bv[2][2];                                                          \
    {                                                                         \
      const short* bp_ = WhT + jg_ + lq * 8;                                  \
      _Pragma("unroll")                                                       \
      for (int kt = 0; kt < 2; ++kt) {                                        \
        bv[kt][0] = *(const bf16x8*)(bp_ + bcol0 + kt * 32);                  \
        bv[kt][1] = *(const bf16x8*)(bp_ + bcol1 + kt * 32);                  \
      }                                                                       \
    }                                                                         \
    {                                                                         \
      const int jl_ = (PH) * 64 + sub * 32;                                   \
      f32x4 ev[8];                                                            \
      _Pragma("unroll")                                                       \
      for (int q = 0; q < 8; ++q) ev[q] = *(const f32x4*)(e2s + jl_ + q * 4); \
      bf16x8 pf[4];                                                           \
      _Pragma("unroll")                                                       \
      for (int i = 0; i < 32; ++i) {                                          \
        float x = e1v + ev[i >> 2][i & 3];                                    \
        float s = fmaxf(x, LRA * x);                                          \
        float p = ((BREG) >> i) & 1 ? __expf(s) : 0.f;                        \
        rs += p;                                                              \
        pf[i >> 3][i & 7] = f2bf(p);                                          \
      }                                                                       \
      char* wb_ = (BUF) + prow * 128;                                         \
      _Pragma("unroll")                                                       \
      for (int c = 0; c < 4; ++c)                                             \
        *(bf16x8*)(wb_ + ((sub * 64 + c * 16) ^ psw)) = pf[c];                \
    }                                                                         \
    __syncthreads();                                                          \
    _Pragma("unroll")                                                         \
    for (int kt = 0; kt < 2; ++kt) {                                          \
      const int ao_ = (kt * 64 + lq * 16) ^ axor;                             \
      _Pragma("unroll")                                                       \
      for (int m = 0; m < 16; ++m) {                                          \
        bf16x8 av = *(const bf16x8*)((BUF) + m * 2048 + lr * 128 + ao_);      \
        acc[m][0] = __builtin_amdgcn_mfma_f32_16x16x32_bf16(av, bv[kt][0], acc[m][0], 0, 0, 0); \
        acc[m][1] = __builtin_amdgcn_mfma_f32_16x16x32_bf16(av, bv[kt][1], acc[m][1], 0, 0, 0); \
      }                                                                       \
    }                                                                         \
  }

__global__ __launch_bounds__(512, 2) void k3_part(const unsigned int* __restrict__ bits32,
                                                  const float* __restrict__ e1,
                                                  const float* __restrict__ e2,
                                                  const short* __restrict__ WhT,
                                                  short* __restrict__ pnum,
                                                  float* __restrict__ pden,
                                                  int nslice) {
  __shared__ __align__(16) char Plds[2][32768];   // 2 x (256 rows x 64 j bf16)
  __shared__ float e2s[1280];
  const int jlen = NPAD / nslice;
  const int s = blockIdx.x % nslice;
  const int rowblk = blockIdx.x / nslice;
  const int jbase = s * jlen;
  const int r0 = rowblk * 256;
  const int t = threadIdx.x;
  const int w = t >> 6, l = t & 63;
  const int lr = l & 15, lq = l >> 4;
  const int prow = t >> 1, sub = t & 1;
  const int psw = (prow & 7) << 4;
  const int axor = (lr & 7) << 4;
  const int growp = r0 + prow;
  const float e1v = e1[growp];                    // zero-padded to NPAD
  const size_t bcol0 = (size_t)(w * 32 + lr) * NPAD;
  const size_t bcol1 = bcol0 + (size_t)16 * NPAD;
  const unsigned int* brow = bits32 + (size_t)growp * (NPAD / 32) + (jbase >> 5) + sub;

  for (int i = t; i < jlen / 4; i += 512)
    ((f32x4*)e2s)[i] = ((const f32x4*)(e2 + jbase))[i];

  f32x4 acc[16][2];
#pragma unroll
  for (int m = 0; m < 16; ++m)
#pragma unroll
    for (int n = 0; n < 2; ++n)
#pragma unroll
      for (int q = 0; q < 4; ++q) acc[m][n][q] = 0.f;
  float rs = 0.f;

  unsigned int bA = brow[0];
  unsigned int bB = brow[2];
  __syncthreads();                                 // e2s ready

  const int nph = jlen >> 6;                       // 10 or 20 (even)
  for (int ph = 0; ph < nph; ph += 2) {
    unsigned int bA2 = (ph + 2 < nph) ? brow[(ph + 2) * 2] : 0u;
    unsigned int bB2 = (ph + 3 < nph) ? brow[(ph + 3) * 2] : 0u;
    K3_PHASE(ph,     bA, &Plds[0][0]);
    K3_PHASE(ph + 1, bB, &Plds[1][0]);
    bA = bA2; bB = bB2;
  }

  rs += __shfl_xor(rs, 1);
  if (sub == 0) pden[(size_t)s * NPAD + growp] = rs;
#pragma unroll
  for (int m = 0; m < 16; ++m)
#pragma unroll
    for (int n = 0; n < 2; ++n)
#pragma unroll
      for (int q = 0; q < 4; ++q) {
        int row = m * 16 + lq * 4 + q;
        pnum[((size_t)s * NPAD + r0 + row) * FOUT + w * 32 + n * 16 + lr] =
            f2bf(acc[m][n][q]);
      }
}

// ---------------- K4: reduce slices, normalize, elu ----------------
__global__ __launch_bounds__(256) void k4_out(const short* __restrict__ pnum,
                                              const float* __restrict__ pden,
                                              float* __restrict__ out,
                                              int nslice) {
  const int row = blockIdx.x;
  const int c = threadIdx.x;
  float den = 0.f;
  for (int s = 0; s < nslice; ++s) den += pden[(size_t)s * NPAD + row];
  float num = 0.f;
  for (int s = 0; s < nslice; ++s)
    num += bf2f(pnum[((size_t)s * NPAD + row) * FOUT + c]);
  float v = num / den;
  out[(size_t)row * FOUT + c] = (v > 0.f) ? v : (__expf(v) - 1.f);
}

// ---------------- Fallback (ws too small): R2 fused k3 ----------------
#define OLD_LOAD(J0N, AV, EV)                                               \
  {                                                                         \
    const int jn_ = (J0N) + jb;                                             \
    EV[0] = *(const f32x4*)(e2 + jn_);                                      \
    EV[1] = *(const f32x4*)(e2 + jn_ + 4);                                  \
    EV[2] = *(const f32x4*)(e2 + jn_ + 128);                                \
    EV[3] = *(const f32x4*)(e2 + jn_ + 132);                                \
    if (rowok && (J0N) + 256 <= NN) {                                       \
      AV[0] = *(const i32x4*)(adj + adjrow + jn_);                          \
      AV[1] = *(const i32x4*)(adj + adjrow + jn_ + 4);                      \
      AV[2] = *(const i32x4*)(adj + adjrow + jn_ + 128);                    \
      AV[3] = *(const i32x4*)(adj + adjrow + jn_ + 132);                    \
    } else {                                                                \
      _Pragma("unroll")                                                     \
      for (int p_ = 0; p_ < 4; ++p_) {                                      \
        _Pragma("unroll")                                                   \
        for (int i_ = 0; i_ < 4; ++i_) {                                    \
          int j_ = jn_ + (p_ >> 1) * 128 + (p_ & 1) * 4 + i_;               \
          AV[p_][i_] = (rowok && j_ < NN) ? adj[adjrow + j_] : 0;           \
        }                                                                   \
      }                                                                     \
    }                                                                       \
  }

#define OLD_PHASE(J0, AV, EV, BUF)                                          \
  {                                                                         \
    bf16x8 pf0, pf1;                                                        \
    _Pragma("unroll")                                                       \
    for (int i = 0; i < 8; ++i) {                                           \
      float x = e1v + EV[i >> 2][i & 3];                                    \
      float s = fmaxf(x, LRA * x);                                          \
      float p = (AV[i >> 2][i & 3] > 0) ? __expf(s) : 0.f;                  \
      rs += p; pf0[i] = f2bf(p);                                            \
    }                                                                       \
    _Pragma("unroll")                                                       \
    for (int i = 0; i < 8; ++i) {                                           \
      float x = e1v + EV[2 + (i >> 2)][i & 3];                              \
      float s = fmaxf(x, LRA * x);                                          \
      float p = (AV[2 + (i >> 2)][i & 3] > 0) ? __expf(s) : 0.f;            \
      rs += p; pf1[i] = f2bf(p);                                            \
    }                                                                       \
    {                                                                       \
      char* wb_ = (BUF) + prow * 512;                                       \
      const int sw_ = (prow & 7) << 4;                                      \
      *(bf16x8*)(wb_ + ((psub * 16) ^ sw_)) = pf0;                          \
      *(bf16x8*)(wb_ + ((256 + psub * 16) ^ sw_)) = pf1;                    \
    }                                                                       \
    __syncthreads();                                                        \
    _Pragma("unroll")                                                       \
    for (int kt = 0; kt < 8; ++kt) {                                        \
      const int boff_ = (kt * 64 + lq * 16) ^ ((lr & 7) << 4);              \
      bf16x8 a0 = *(const bf16x8*)((BUF) + lr * 512 + boff_);               \
      bf16x8 a1 = *(const bf16x8*)((BUF) + (16 + lr) * 512 + boff_);        \
      const short* bp_ = WhT + (J0) + kt * 32 + lq * 8;                     \
      bf16x8 b0 = *(const bf16x8*)(bp_ + bcol0);                            \
      bf16x8 b1 = *(const bf16x8*)(bp_ + bcol1);                            \
      acc[0][0] = __builtin_amdgcn_mfma_f32_16x16x32_bf16(a0, b0, acc[0][0], 0, 0, 0); \
      acc[1][0] = __builtin_amdgcn_mfma_f32_16x16x32_bf16(a1, b0, acc[1][0], 0, 0, 0); \
      acc[0][1] = __builtin_amdgcn_mfma_f32_16x16x32_bf16(a0, b1, acc[0][1], 0, 0, 0); \
      acc[1][1] = __builtin_amdgcn_mfma_f32_16x16x32_bf16(a1, b1, acc[1][1], 0, 0, 0); \
    }                                                                       \
  }

__global__ __launch_bounds__(512) void k3_old(const int* __restrict__ adj,
                                              const float* __restrict__ e1,
                                              const float* __restrict__ e2,
                                              const short* __restrict__ WhT,
                                              float* __restrict__ out) {
  __shared__ __align__(16) char Plds[2][32 * 512];
  __shared__ float rowsum[32];
  const int r0 = blockIdx.x * 32;
  const int t = threadIdx.x;
  const int w = t >> 6, l = t & 63;
  const int lr = l & 15, lq = l >> 4;
  const int prow = t >> 4;
  const int psub = t & 15;
  const int jb = psub * 8;
  const int gr = r0 + prow;
  const bool rowok = (gr < NN);
  const float e1v = rowok ? e1[gr] : 0.f;
  const size_t adjrow = (size_t)gr * NN;
  const size_t bcol0 = (size_t)(w * 32 + lr) * NPAD;
  const size_t bcol1 = (size_t)(w * 32 + 16 + lr) * NPAD;
  float rs = 0.f;
  f32x4 acc[2][2];
#pragma unroll
  for (int m = 0; m < 2; ++m)
#pragma unroll
    for (int n = 0; n < 2; ++n)
#pragma unroll
      for (int q = 0; q < 4; ++q) acc[m][n][q] = 0.f;

  const int NT = (NN + 255) / 256;
  i32x4 avA[4], avB[4];
  f32x4 evA[4], evB[4];
  OLD_LOAD(0, avA, evA);
  for (int jt = 0; jt < NT; jt += 2) {
    OLD_LOAD((jt + 1) * 256, avB, evB);
    OLD_PHASE(jt * 256, avA, evA, &Plds[0][0]);
    if (jt + 2 < NT) OLD_LOAD((jt + 2) * 256, avA, evA);
    OLD_PHASE((jt + 1) * 256, avB, evB, &Plds[1][0]);
  }
  rs += __shfl_xor(rs, 1); rs += __shfl_xor(rs, 2);
  rs += __shfl_xor(rs, 4); rs += __shfl_xor(rs, 8);
  if (psub == 0) rowsum[prow] = rs;
  __syncthreads();
#pragma unroll
  for (int m = 0; m < 2; ++m)
#pragma unroll
    for (int n = 0; n < 2; ++n)
#pragma unroll
      for (int q = 0; q < 4; ++q) {
        int row = m * 16 + lq * 4 + q;
        int grow = r0 + row;
        if (grow < NN) {
          float v = acc[m][n][q] / rowsum[row];
          float o = (v > 0.f) ? v : (__expf(v) - 1.f);
          out[(size_t)grow * FOUT + w * 32 + n * 16 + lr] = o;
        }
      }
}

extern "C" void kernel_launch(void* const* d_in, const int* in_sizes, int n_in,
                              void* d_out, int out_size, void* d_ws, size_t ws_size,
                              hipStream_t stream) {
  const float* h   = (const float*)d_in[0];
  const int*   adj = (const int*)d_in[1];
  const float* W   = (const float*)d_in[2];
  const float* a   = (const float*)d_in[3];
  float* out = (float*)d_out;
  char* ws = (char*)d_ws;
  _Float16* Wt  = (_Float16*)(ws + 0);            // 262144
  float*    Wh  = (float*)(ws + 262144);          // -> 10502144
  short*    WhT = (short*)(ws + 10502144);        // -> 15745024
  float*    e1  = (float*)(ws + 15745024);        // -> 15785984
  float*    e2  = (float*)(ws + 15785984);        // -> 15826944
  unsigned long long* bits = (unsigned long long*)(ws + 15826944);  // 13107200 -> 28934144
  (void)in_sizes; (void)n_in; (void)out_size;

  int nslice = 0;
  if (ws_size >= (size_t)113475584) nslice = 16;
  else if (ws_size >= (size_t)71204864) nslice = 8;

  k0_wt<<<dim3(512), dim3(256), 0, stream>>>(W, Wt);
  k1_wh<<<dim3(157), dim3(256), 0, stream>>>(h, Wt, Wh);
  k2_et<<<dim3(160), dim3(256), 0, stream>>>(Wh, a, e1, e2, WhT);

  if (nslice) {
    float* pden = (float*)(ws + 28934144);                          // nslice*40960
    short* pnum = (short*)(ws + 28934144 + (size_t)nslice * NPAD * 4);
    kp_bits<<<dim3(2048), dim3(256), 0, stream>>>(adj, bits);
    k3_part<<<dim3(40 * nslice), dim3(512), 0, stream>>>(
        (const unsigned int*)bits, e1, e2, WhT, pnum, pden, nslice);
    k4_out<<<dim3(NN), dim3(256), 0, stream>>>(pnum, pden, out, nslice);
  } else {
    k3_old<<<dim3(313), dim3(512), 0, stream>>>(adj, e1, e2, WhT, out);
  }
}